// Round 2
// baseline (80.722 us; speedup 1.0000x reference)
//
#include <hip/hip_runtime.h>

// Problem constants (from the reference)
#define B_    8
#define C_    8
#define L_    4096
#define F_    32
#define K_    10
#define PROC_ 20
#define STEP_ 5
#define NW_   815   // len(range(0, L-PROC-STEP+1, STEP)); CHAN_OUT == NW_ (no pad region)

typedef float v2f __attribute__((ext_vector_type(2)));

__global__ __launch_bounds__(256) void dtw_kernel(
    const float* __restrict__ x,      // (B, C, L)
    const float* __restrict__ kern,   // (F, K)
    float* __restrict__ out)          // (B, C*F, NW)
{
    __shared__ float sx[L_];

    const int blk = blockIdx.x;          // 0 .. B*C*F-1
    const int f = blk & (F_ - 1);        // fastest
    const int c = (blk >> 5) & (C_ - 1);
    const int b = blk >> 8;

    // Stage x[b][c][:] into LDS with float4 loads (4096 floats = 1024 float4)
    const float4* x4 = reinterpret_cast<const float4*>(x + ((size_t)(b * C_ + c)) * L_);
    float4* s4 = reinterpret_cast<float4*>(sx);
    #pragma unroll
    for (int i = 0; i < L_ / 4 / 256; ++i)
        s4[threadIdx.x + i * 256] = x4[threadIdx.x + i * 256];

    // Kernel taps: block-uniform (f from blockIdx) -> scalar regs
    float kk[K_];
    #pragma unroll
    for (int i = 0; i < K_; ++i) kk[i] = kern[f * K_ + i];

    __syncthreads();

    float* outp = out + ((size_t)b * (C_ * F_) + (c * F_ + f)) * (size_t)NW_;
    const int tid = threadIdx.x;

    // Two rounds; each round runs TWO windows per thread packed in a float2.
    // Round 0: w0 = tid       (<=255, valid), w1 = tid+256 (<=511, valid)
    // Round 1: w0 = tid+512   (<=767, valid), w1 = tid+768 (valid iff tid<47)
    #pragma unroll
    for (int r = 0; r < 2; ++r) {
        const int w0 = tid + r * 512;
        const int w1r = w0 + 256;
        const bool w1ok = (w1r < NW_);
        const int w1 = w1ok ? w1r : (NW_ - 1);   // clamp loads for dead lanes

        const float* pa = sx + w0 * STEP_;
        const float* pb = sx + w1 * STEP_;

        v2f wv[PROC_];
        #pragma unroll
        for (int j = 0; j < PROC_; ++j) {
            v2f t; t.x = pa[j]; t.y = pb[j];
            wv[j] = t;
        }

        v2f row[PROC_];
        // row0 = cumsum((kk[0]-wv)^2)  -> v_pk_add(neg) + v_pk_fma chains
        {
            v2f d = kk[0] - wv[0];
            row[0] = d * d;
            #pragma unroll
            for (int j = 1; j < PROC_; ++j) {
                v2f dj = kk[0] - wv[j];
                row[j] = dj * dj + row[j - 1];
            }
        }
        // rows 1..K-1: cur = d^2 + min(left, up, diag)
        #pragma unroll
        for (int i = 1; i < K_; ++i) {
            v2f diag = row[0];
            v2f d0 = kk[i] - wv[0];
            v2f cur = d0 * d0 + diag;
            row[0] = cur;
            v2f left = cur;
            #pragma unroll
            for (int j = 1; j < PROC_; ++j) {
                v2f up = row[j];
                v2f dj = kk[i] - wv[j];
                v2f m = __builtin_elementwise_min(__builtin_elementwise_min(left, up), diag);
                cur = dj * dj + m;
                diag = up;
                row[j] = cur;
                left = cur;
            }
        }
        outp[w0] = row[PROC_ - 1].x;        // w0 always valid (<= 767)
        if (w1ok) outp[w1r] = row[PROC_ - 1].y;
    }
}

extern "C" void kernel_launch(void* const* d_in, const int* in_sizes, int n_in,
                              void* d_out, int out_size, void* d_ws, size_t ws_size,
                              hipStream_t stream) {
    const float* x    = (const float*)d_in[0];   // (8, 8, 4096) fp32
    const float* kern = (const float*)d_in[1];   // (32, 10) fp32
    float* out        = (float*)d_out;           // (8, 256, 815) fp32

    dim3 grid(B_ * C_ * F_);   // 2048 blocks
    dim3 block(256);
    hipLaunchKernelGGL(dtw_kernel, grid, block, 0, stream, x, kern, out);
}

// Round 4
// 79.453 us; speedup vs baseline: 1.0160x; 1.0160x over previous
//
#include <hip/hip_runtime.h>

// Problem constants (from the reference)
#define B_    8
#define C_    8
#define L_    4096
#define F_    32
#define K_    10
#define PROC_ 20
#define STEP_ 5
#define NW_   815   // len(range(0, L-PROC-STEP+1, STEP)); CHAN_OUT == NW_ (no pad region)

// Packed half2 via clang native vector type: ops lower to v_pk_*_f16.
typedef _Float16 h2 __attribute__((ext_vector_type(2)));

// Latency/occupancy-bound kernel: two windows per thread packed in h2,
// keeping state to ~50 VGPRs so occupancy stays high.
__global__ __launch_bounds__(256, 6) void dtw_kernel(
    const float* __restrict__ x,      // (B, C, L)
    const float* __restrict__ kern,   // (F, K)
    float* __restrict__ out)          // (B, C*F, NW)
{
    __shared__ float sx[L_];

    const int blk = blockIdx.x;          // 0 .. B*C*F-1
    const int f = blk & (F_ - 1);        // fastest
    const int c = (blk >> 5) & (C_ - 1);
    const int b = blk >> 8;

    // Stage x[b][c][:] into LDS with float4 loads (4096 floats = 1024 float4)
    const float4* x4 = reinterpret_cast<const float4*>(x + ((size_t)(b * C_ + c)) * L_);
    float4* s4 = reinterpret_cast<float4*>(sx);
    #pragma unroll
    for (int i = 0; i < L_ / 4 / 256; ++i)
        s4[threadIdx.x + i * 256] = x4[threadIdx.x + i * 256];

    // Kernel taps, broadcast to both halves (block-uniform loads)
    h2 kk[K_];
    #pragma unroll
    for (int i = 0; i < K_; ++i) {
        _Float16 kv = (_Float16)kern[f * K_ + i];
        h2 t; t.x = kv; t.y = kv;
        kk[i] = t;
    }

    __syncthreads();

    float* outp = out + ((size_t)b * (C_ * F_) + (c * F_ + f)) * (size_t)NW_;
    const int tid = threadIdx.x;

    // Round 0: windows (tid, tid+256)         both valid
    // Round 1: windows (tid+512, tid+768)     second valid iff tid < 47
    #pragma unroll
    for (int r = 0; r < 2; ++r) {
        const int w0 = tid + r * 512;
        const int w1r = w0 + 256;
        const bool w1ok = (w1r < NW_);
        const int w1 = w1ok ? w1r : (NW_ - 1);   // clamp loads for dead lanes

        const float* pa = sx + w0 * STEP_;
        const float* pb = sx + w1 * STEP_;

        // Window values: low half = window w0, high half = window w1
        h2 wv[PROC_];
        #pragma unroll
        for (int j = 0; j < PROC_; ++j) {
            h2 t; t.x = (_Float16)pa[j]; t.y = (_Float16)pb[j];
            wv[j] = t;
        }

        h2 row[PROC_];
        // row0 = cumsum((kk[0]-wv)^2)
        {
            h2 d = kk[0] - wv[0];
            row[0] = d * d;
            #pragma unroll
            for (int j = 1; j < PROC_; ++j) {
                h2 dj = kk[0] - wv[j];
                row[j] = dj * dj + row[j - 1];
            }
        }
        // rows 1..K-1: cur = d^2 + min(left, up, diag)
        #pragma unroll
        for (int i = 1; i < K_; ++i) {
            h2 diag = row[0];
            h2 d0 = kk[i] - wv[0];
            h2 cur = d0 * d0 + diag;
            row[0] = cur;
            h2 left = cur;
            #pragma unroll
            for (int j = 1; j < PROC_; ++j) {
                h2 up = row[j];
                h2 dj = kk[i] - wv[j];
                h2 m = __builtin_elementwise_min(__builtin_elementwise_min(left, up), diag);
                cur = dj * dj + m;
                diag = up;
                row[j] = cur;
                left = cur;
            }
        }
        outp[w0] = (float)row[PROC_ - 1].x;          // w0 always valid (<=767)
        if (w1ok) outp[w1r] = (float)row[PROC_ - 1].y;
    }
}

extern "C" void kernel_launch(void* const* d_in, const int* in_sizes, int n_in,
                              void* d_out, int out_size, void* d_ws, size_t ws_size,
                              hipStream_t stream) {
    const float* x    = (const float*)d_in[0];   // (8, 8, 4096) fp32
    const float* kern = (const float*)d_in[1];   // (32, 10) fp32
    float* out        = (float*)d_out;           // (8, 256, 815) fp32

    dim3 grid(B_ * C_ * F_);   // 2048 blocks
    dim3 block(256);
    hipLaunchKernelGGL(dtw_kernel, grid, block, 0, stream, x, kern, out);
}

// Round 5
// 74.033 us; speedup vs baseline: 1.0903x; 1.0732x over previous
//
#include <hip/hip_runtime.h>

// Problem constants (from the reference)
#define B_    8
#define C_    8
#define L_    4096
#define F_    32
#define K_    10
#define PROC_ 20
#define STEP_ 5
#define NW_   815   // len(range(0, L-PROC-STEP+1, STEP)); CHAN_OUT == NW_ (no pad region)

// One DTW: kernel taps kk[] (scalar, block-uniform) vs 20-float window at win.
// 3 VALU ops/cell: v_sub, v_min3, v_fma. Returns acc[K-1][P-1].
__device__ __forceinline__ float dtw_one(const float* __restrict__ win,
                                         const float kk[K_])
{
    float wv[PROC_];
    #pragma unroll
    for (int j = 0; j < PROC_; ++j) wv[j] = win[j];

    float row[PROC_];
    {
        float d = kk[0] - wv[0];
        row[0] = d * d;
        #pragma unroll
        for (int j = 1; j < PROC_; ++j) {
            float dj = kk[0] - wv[j];
            row[j] = fmaf(dj, dj, row[j - 1]);
        }
    }
    #pragma unroll
    for (int i = 1; i < K_; ++i) {
        float diag = row[0];
        float d0 = kk[i] - wv[0];
        float cur = fmaf(d0, d0, diag);
        row[0] = cur;
        float left = cur;
        #pragma unroll
        for (int j = 1; j < PROC_; ++j) {
            float up = row[j];
            float dj = kk[i] - wv[j];
            float m = fminf(fminf(left, up), diag);  // v_min3_f32
            cur = fmaf(dj, dj, m);
            diag = up;
            row[j] = cur;
            left = cur;
        }
    }
    return row[PROC_ - 1];
}

// Force 8 waves/SIMD (64-VGPR cap). State: wv[20]+row[20]=40 VGPR, kk->SGPR.
__global__ __launch_bounds__(256, 8) void dtw_kernel(
    const float* __restrict__ x,      // (B, C, L)
    const float* __restrict__ kern,   // (F, K)
    float* __restrict__ out)          // (B, C*F, NW)
{
    __shared__ float sx[L_];

    const int blk = blockIdx.x;          // 0 .. B*C*F-1
    const int f = blk & (F_ - 1);        // fastest
    const int c = (blk >> 5) & (C_ - 1);
    const int b = blk >> 8;

    // Stage x[b][c][:] into LDS with float4 loads (4096 floats = 1024 float4)
    const float4* x4 = reinterpret_cast<const float4*>(x + ((size_t)(b * C_ + c)) * L_);
    float4* s4 = reinterpret_cast<float4*>(sx);
    #pragma unroll
    for (int i = 0; i < L_ / 4 / 256; ++i)
        s4[threadIdx.x + i * 256] = x4[threadIdx.x + i * 256];

    // Kernel taps: block-uniform loads -> s_load / SGPRs
    float kk[K_];
    #pragma unroll
    for (int i = 0; i < K_; ++i) kk[i] = kern[f * K_ + i];

    __syncthreads();

    float* outp = out + ((size_t)b * (C_ * F_) + (c * F_ + f)) * (size_t)NW_;
    const int tid = threadIdx.x;

    // 3 uniform rounds: w = tid, tid+256, tid+512 (max 767 < 815) — no masking.
    #pragma unroll
    for (int r = 0; r < 3; ++r) {
        const int w = tid + r * 256;
        outp[w] = dtw_one(sx + w * STEP_, kk);
    }
    // Masked tail: w = tid + 768, valid iff tid < 47.
    {
        const int w = tid + 768;
        if (w < NW_) outp[w] = dtw_one(sx + w * STEP_, kk);
    }
}

extern "C" void kernel_launch(void* const* d_in, const int* in_sizes, int n_in,
                              void* d_out, int out_size, void* d_ws, size_t ws_size,
                              hipStream_t stream) {
    const float* x    = (const float*)d_in[0];   // (8, 8, 4096) fp32
    const float* kern = (const float*)d_in[1];   // (32, 10) fp32
    float* out        = (float*)d_out;           // (8, 256, 815) fp32

    dim3 grid(B_ * C_ * F_);   // 2048 blocks
    dim3 block(256);
    hipLaunchKernelGGL(dtw_kernel, grid, block, 0, stream, x, kern, out);
}